// Round 7
// baseline (372.067 us; speedup 1.0000x reference)
//
#include <hip/hip_runtime.h>
#include <cstdint>
#include <cstddef>

#define C_CH 128
#define T_TOK 9216
#define H_IMG 96
#define W_IMG 96
#define NSTATE 8

// fused scan tiling: 64 output tokens, 32-token warm-up halo each direction
#define CHUNK 64
#define RHALO 32

// k1 GEMM tiling
#define MT 128
#define NT 128
#define KS 32

__device__ __forceinline__ float siluf_dev(float x) {
  return x / (1.0f + expf(-x));
}

// ---------------------------------------------------------------------------
// K0: slot map + v = out_proj_w @ mlp_w + Bf = in_proj with rms_w folded
// ---------------------------------------------------------------------------
__global__ __launch_bounds__(256) void k0_setup(
    const int* __restrict__ rec, int n_groups, int N,
    const float* __restrict__ out_proj_w, const float* __restrict__ mlp_w,
    const float* __restrict__ in_proj, const float* __restrict__ rms_w,
    float* __restrict__ vvec, int* __restrict__ slot, float* __restrict__ Bf)
{
  const int tid = threadIdx.x;
  if (tid == 0) {
    int f = 0, sl = 0;
    for (int g = 0; g < n_groups; ++g) {
      const int L = rec[g];
      slot[f] = -1;                       // ego / single frame -> mask = 1
      for (int i = 1; i < L; ++i) slot[f + i] = sl++;
      f += L;
    }
  }
  if (tid < C_CH) {
    float acc = 0.0f;
    for (int j = 0; j < C_CH; ++j) acc += out_proj_w[tid * C_CH + j] * mlp_w[j];
    vvec[tid] = acc;
  }
  for (int idx = tid; idx < C_CH * 256; idx += 256) {
    const int k = idx >> 8;
    Bf[idx] = in_proj[idx] * rms_w[k];
  }
}

// ---------------------------------------------------------------------------
// K1: fused rmsnorm + xz = xn @ in_proj.  128x128 tile, K=128 in 4x32 steps,
// 8x8 micro-tiles (VALU-bound). rms_w pre-folded into Bf; invrms computed
// incrementally from staged A tiles and applied at epilogue. Also emits
// logit_init = res.mlp_w + b (nchunk 0 only).
// nchunk 0 -> xipre[t][c]; nchunk 1 -> w[t][c] = 0.5*silu(z)*v[c].
// ---------------------------------------------------------------------------
__global__ __launch_bounds__(256, 4) void k1_gemm(
    const float* __restrict__ feats, const float* __restrict__ Bf,
    const float* __restrict__ mlp_w, const float* __restrict__ mlp_b,
    const float* __restrict__ vvec, const int* __restrict__ slot,
    float* __restrict__ xipre, float* __restrict__ wbuf,
    float* __restrict__ logit)
{
  __shared__ float Asm[KS * MT];     // [k][m] 16 KB (raw feats)
  __shared__ float Bsm[KS * NT];     // [k][j] 16 KB (rms-folded)
  __shared__ float redS[256], redR[256], irS[MT];
  const int f = blockIdx.z;
  const int s = slot[f];
  if (s < 0) return;
  const int m0 = blockIdx.x * MT;
  const int nch = blockIdx.y;
  const int j0 = nch * NT;
  const int tid = threadIdx.x;
  const int tm = tid & 15;           // rows tm*8..+7
  const int tn = tid >> 4;           // cols tn*8..+7
  const size_t fbase = (size_t)f * C_CH * T_TOK;
  const size_t rowbase = (size_t)s * T_TOK;

  float acc[8][8];
  #pragma unroll
  for (int i = 0; i < 8; ++i)
    #pragma unroll
    for (int j = 0; j < 8; ++j) acc[i][j] = 0.0f;
  float ssum = 0.0f, rmsum = 0.0f;
  const int tokA = tid & 127;
  const int khalf = tid >> 7;        // wave-uniform

  for (int ks = 0; ks < 4; ++ks) {
    const int k0 = ks * KS;
    __syncthreads();
    #pragma unroll
    for (int i = 0; i < 4; ++i) {
      const int idx = tid + 256 * i;
      const int r = idx >> 5;
      const int q = (idx & 31) * 4;
      *(float4*)&Asm[r * MT + q] =
          *(const float4*)&feats[fbase + (size_t)(k0 + r) * T_TOK + m0 + q];
      *(float4*)&Bsm[r * NT + q] =
          *(const float4*)&Bf[(k0 + r) * 256 + j0 + q];
    }
    __syncthreads();
    // incremental rms / residual-dot partials (16 k's per thread)
    #pragma unroll
    for (int kk = 0; kk < 16; ++kk) {
      const int k = khalf * 16 + kk;
      const float v = Asm[k * MT + tokA];
      ssum = fmaf(v, v, ssum);
      rmsum = fmaf(v, mlp_w[k0 + k], rmsum);
    }
    // 8x8 FMA loop
    #pragma unroll 8
    for (int k = 0; k < KS; ++k) {
      const float4 a0 = *(const float4*)&Asm[k * MT + tm * 8];
      const float4 a1 = *(const float4*)&Asm[k * MT + tm * 8 + 4];
      const float4 b0 = *(const float4*)&Bsm[k * NT + tn * 8];
      const float4 b1 = *(const float4*)&Bsm[k * NT + tn * 8 + 4];
      const float ar[8] = {a0.x, a0.y, a0.z, a0.w, a1.x, a1.y, a1.z, a1.w};
      const float br[8] = {b0.x, b0.y, b0.z, b0.w, b1.x, b1.y, b1.z, b1.w};
      #pragma unroll
      for (int i = 0; i < 8; ++i)
        #pragma unroll
        for (int j = 0; j < 8; ++j)
          acc[i][j] = fmaf(ar[i], br[j], acc[i][j]);
    }
  }
  redS[tid] = ssum; redR[tid] = rmsum;
  __syncthreads();
  if (tid < 128) {
    const float ss = redS[tid] + redS[tid + 128];
    irS[tid] = 1.0f / sqrtf(ss * (1.0f / C_CH) + 1e-5f);
    if (nch == 0)
      logit[rowbase + m0 + tid] = redR[tid] + redR[tid + 128] + mlp_b[0];
  }
  __syncthreads();

  if (nch == 0) {
    #pragma unroll
    for (int i = 0; i < 8; ++i) {
      const int t = m0 + tm * 8 + i;
      const float irv = irS[tm * 8 + i];
      float4 o0, o1;
      o0.x = acc[i][0] * irv; o0.y = acc[i][1] * irv;
      o0.z = acc[i][2] * irv; o0.w = acc[i][3] * irv;
      o1.x = acc[i][4] * irv; o1.y = acc[i][5] * irv;
      o1.z = acc[i][6] * irv; o1.w = acc[i][7] * irv;
      float* dst = &xipre[(rowbase + t) * C_CH + tn * 8];
      *(float4*)dst = o0;
      *(float4*)(dst + 4) = o1;
    }
  } else {
    const float4 v0 = *(const float4*)&vvec[tn * 8];
    const float4 v1 = *(const float4*)&vvec[tn * 8 + 4];
    const float vr[8] = {v0.x, v0.y, v0.z, v0.w, v1.x, v1.y, v1.z, v1.w};
    #pragma unroll
    for (int i = 0; i < 8; ++i) {
      const int t = m0 + tm * 8 + i;
      const float irv = irS[tm * 8 + i];
      float o[8];
      #pragma unroll
      for (int j = 0; j < 8; ++j) {
        const float z = acc[i][j] * irv;
        o[j] = 0.5f * (z / (1.0f + __expf(-z))) * vr[j];
      }
      float* dst = &wbuf[(rowbase + t) * C_CH + tn * 8];
      *(float4*)dst = *(float4*)&o[0];
      *(float4*)(dst + 4) = *(float4*)&o[4];
    }
  }
}

// ---------------------------------------------------------------------------
// K3_fused: conv + projection + bidirectional chunked scan in ONE kernel.
// Block = 256 threads, 64 output tokens [c0, c0+64), region = [c0-32, c0+96).
// Phase A (4 passes x 32 region rows, 16.5 KB xibuf): conv+silu -> xibuf,
//   then 128->24 projection -> dbl. Scan: waves 0-1 fwd, 2-3 bwd; conv via
//   rolling register window; h[8] in VGPRs; exp(d*A_n) = r^(n+1) when A is
//   harmonic (runtime-checked, generic fallback). Halo trunc ~1e-9.
// ---------------------------------------------------------------------------
__global__ __launch_bounds__(256, 5) void k3_fused(
    const float* __restrict__ xipre, const float* __restrict__ wbuf,
    const float* __restrict__ conv_w, const float* __restrict__ conv_b,
    const float* __restrict__ x_proj_w,
    const float* __restrict__ dt_proj_w, const float* __restrict__ dt_proj_b,
    const float* __restrict__ A_log_f, const float* __restrict__ A_log_b,
    const float* __restrict__ D_f, const float* __restrict__ D_b,
    const int* __restrict__ slot, float* __restrict__ logit)
{
  __shared__ float xibuf[32 * 129];     // 16.5 KB
  __shared__ float dbl[128 * 24];       // 12.3 KB [region_row][dt|B|C]
  const int f = blockIdx.y;
  const int s = slot[f];
  if (s < 0) return;
  const int c0 = blockIdx.x * CHUNK;
  const int r0 = c0 - RHALO;
  const int tid = threadIdx.x;
  const int c = tid & 127;
  const int half = tid >> 7;            // 0 = fwd waves, 1 = bwd waves
  const size_t rowbase = (size_t)s * T_TOK;
  const float4 cw = *(const float4*)(conv_w + c * 4);
  const float cb = conv_b[c];

  auto ldx = [&](int t) -> float {
    return (t >= 0 && t < T_TOK) ? xipre[(rowbase + t) * C_CH + c] : 0.0f;
  };

  // ---- Phase A: conv + projection over the 128-row region, 4 passes ----
  const int q6 = __builtin_amdgcn_readfirstlane(tid >> 6) * 6;
  const int tok = tid & 63;
  for (int pass = 0; pass < 4; ++pass) {
    __syncthreads();
    {
      const int pr0 = pass * 32 + half * 16;
      float xm1 = ldx(r0 + pr0 - 1);
      float xm2 = ldx(r0 + pr0 - 2);
      float xm3 = ldx(r0 + pr0 - 3);
      for (int i = 0; i < 16; ++i) {
        const float cur = ldx(r0 + pr0 + i);
        const float sum = cw.x * xm3 + cw.y * xm2 + cw.z * xm1 + cw.w * cur + cb;
        xibuf[(half * 16 + i) * 129 + c] = sum / (1.0f + __expf(-sum));
        xm3 = xm2; xm2 = xm1; xm1 = cur;
      }
    }
    __syncthreads();
    if (tok < 32) {
      float acc[6] = {0, 0, 0, 0, 0, 0};
      for (int cc = 0; cc < C_CH; ++cc) {
        const float xv = xibuf[tok * 129 + cc];
        #pragma unroll
        for (int jj = 0; jj < 6; ++jj)
          acc[jj] += xv * x_proj_w[cc * 24 + q6 + jj];
      }
      #pragma unroll
      for (int jj = 0; jj < 6; ++jj)
        dbl[(pass * 32 + tok) * 24 + q6 + jj] = acc[jj];
    }
  }
  __syncthreads();

  // ---- Scan phase ----
  float dw[8], Ac[8];
  const float* Alog = half ? A_log_b : A_log_f;
  #pragma unroll
  for (int r = 0; r < 8; ++r) dw[r] = dt_proj_w[r * C_CH + c];
  #pragma unroll
  for (int n = 0; n < NSTATE; ++n) Ac[n] = -expf(Alog[c * NSTATE + n]);
  bool fa = true;
  #pragma unroll
  for (int n = 0; n < NSTATE; ++n)
    fa = fa && (fabsf(Ac[n] - (n + 1) * Ac[0]) < 1e-5f * (n + 1));
  const bool fast = (__ballot(fa) == 0xFFFFFFFFFFFFFFFFull);
  const float bias = dt_proj_b[c];
  const float Dd = half ? D_b[c] : D_f[c];
  float h[8] = {0, 0, 0, 0, 0, 0, 0, 0};

  if (half == 0) {
    const int tb = (r0 < 0) ? 0 : r0;
    const int steps = c0 + CHUNK - tb;
    const int outg0 = (c0 - tb) >> 3;
    const int ng = steps >> 3;
    float xm1 = ldx(tb - 1), xm2 = ldx(tb - 2), xm3 = ldx(tb - 3);
    for (int g = 0; g < ng; ++g) {
      const int t0 = tb + g * 8;
      const bool out = (g >= outg0);
      float pg[8], wg[8];
      #pragma unroll
      for (int j = 0; j < 8; ++j) {
        const size_t gi = (rowbase + t0 + j) * C_CH + c;
        pg[j] = xipre[gi];
        wg[j] = out ? wbuf[gi] : 0.0f;
      }
      #pragma unroll
      for (int j = 0; j < 8; ++j) {
        const int t = t0 + j;
        const int p = t - r0;
        const float cur = pg[j];
        const float sum = cw.x * xm3 + cw.y * xm2 + cw.z * xm1 + cw.w * cur + cb;
        const float xiv = sum / (1.0f + __expf(-sum));
        xm3 = xm2; xm2 = xm1; xm1 = cur;
        const float4 d0 = *(const float4*)&dbl[p * 24];
        const float4 d1 = *(const float4*)&dbl[p * 24 + 4];
        float pre = bias;
        pre += d0.x * dw[0] + d0.y * dw[1] + d0.z * dw[2] + d0.w * dw[3];
        pre += d1.x * dw[4] + d1.y * dw[5] + d1.z * dw[6] + d1.w * dw[7];
        const float dlt = fmaxf(pre, 0.0f) + __logf(1.0f + __expf(-fabsf(pre)));
        const float u = dlt * xiv;
        float e[8];
        if (fast) {
          const float r1 = __expf(dlt * Ac[0]);
          e[0] = r1; e[1] = r1 * r1; e[2] = e[1] * r1; e[3] = e[2] * r1;
          e[4] = e[3] * r1; e[5] = e[4] * r1; e[6] = e[5] * r1; e[7] = e[6] * r1;
        } else {
          #pragma unroll
          for (int n = 0; n < 8; ++n) e[n] = __expf(dlt * Ac[n]);
        }
        const float4 b0 = *(const float4*)&dbl[p * 24 + 8];
        const float4 b1 = *(const float4*)&dbl[p * 24 + 12];
        h[0] = e[0] * h[0] + u * b0.x; h[1] = e[1] * h[1] + u * b0.y;
        h[2] = e[2] * h[2] + u * b0.z; h[3] = e[3] * h[3] + u * b0.w;
        h[4] = e[4] * h[4] + u * b1.x; h[5] = e[5] * h[5] + u * b1.y;
        h[6] = e[6] * h[6] + u * b1.z; h[7] = e[7] * h[7] + u * b1.w;
        if (out) {
          const float4 cc0 = *(const float4*)&dbl[p * 24 + 16];
          const float4 cc1 = *(const float4*)&dbl[p * 24 + 20];
          float y = xiv * Dd;
          y += h[0] * cc0.x + h[1] * cc0.y + h[2] * cc0.z + h[3] * cc0.w;
          y += h[4] * cc1.x + h[5] * cc1.y + h[6] * cc1.z + h[7] * cc1.w;
          float contrib = y * wg[j];
          contrib += __shfl_xor(contrib, 1);
          contrib += __shfl_xor(contrib, 2);
          contrib += __shfl_xor(contrib, 4);
          contrib += __shfl_xor(contrib, 8);
          contrib += __shfl_xor(contrib, 16);
          contrib += __shfl_xor(contrib, 32);
          if ((tid & 63) == 0) atomicAdd(&logit[rowbase + t], contrib);
        }
      }
    }
  } else {
    const int te2e = r0 + 128;
    const int te2 = (te2e > T_TOK) ? T_TOK : te2e;
    const int steps = te2 - c0;
    const int outg0 = (te2 - (c0 + CHUNK)) >> 3;
    const int ng = steps >> 3;
    float w0 = ldx(te2 - 1), w1 = ldx(te2 - 2), w2 = ldx(te2 - 3), w3 = ldx(te2 - 4);
    for (int g = 0; g < ng; ++g) {
      const int t0 = te2 - 1 - g * 8;
      const bool out = (g >= outg0);
      float nv[8], wg[8];
      #pragma unroll
      for (int j = 0; j < 8; ++j) {
        nv[j] = ldx(t0 - 4 - j);
        wg[j] = out ? wbuf[(rowbase + t0 - j) * C_CH + c] : 0.0f;
      }
      #pragma unroll
      for (int j = 0; j < 8; ++j) {
        const int t = t0 - j;
        const int p = t - r0;
        const float sum = cw.x * w3 + cw.y * w2 + cw.z * w1 + cw.w * w0 + cb;
        const float xiv = sum / (1.0f + __expf(-sum));
        w0 = w1; w1 = w2; w2 = w3; w3 = nv[j];
        const float4 d0 = *(const float4*)&dbl[p * 24];
        const float4 d1 = *(const float4*)&dbl[p * 24 + 4];
        float pre = bias;
        pre += d0.x * dw[0] + d0.y * dw[1] + d0.z * dw[2] + d0.w * dw[3];
        pre += d1.x * dw[4] + d1.y * dw[5] + d1.z * dw[6] + d1.w * dw[7];
        const float dlt = fmaxf(pre, 0.0f) + __logf(1.0f + __expf(-fabsf(pre)));
        const float u = dlt * xiv;
        float e[8];
        if (fast) {
          const float r1 = __expf(dlt * Ac[0]);
          e[0] = r1; e[1] = r1 * r1; e[2] = e[1] * r1; e[3] = e[2] * r1;
          e[4] = e[3] * r1; e[5] = e[4] * r1; e[6] = e[5] * r1; e[7] = e[6] * r1;
        } else {
          #pragma unroll
          for (int n = 0; n < 8; ++n) e[n] = __expf(dlt * Ac[n]);
        }
        const float4 b0 = *(const float4*)&dbl[p * 24 + 8];
        const float4 b1 = *(const float4*)&dbl[p * 24 + 12];
        h[0] = e[0] * h[0] + u * b0.x; h[1] = e[1] * h[1] + u * b0.y;
        h[2] = e[2] * h[2] + u * b0.z; h[3] = e[3] * h[3] + u * b0.w;
        h[4] = e[4] * h[4] + u * b1.x; h[5] = e[5] * h[5] + u * b1.y;
        h[6] = e[6] * h[6] + u * b1.z; h[7] = e[7] * h[7] + u * b1.w;
        if (out) {
          const float4 cc0 = *(const float4*)&dbl[p * 24 + 16];
          const float4 cc1 = *(const float4*)&dbl[p * 24 + 20];
          float y = xiv * Dd;
          y += h[0] * cc0.x + h[1] * cc0.y + h[2] * cc0.z + h[3] * cc0.w;
          y += h[4] * cc1.x + h[5] * cc1.y + h[6] * cc1.z + h[7] * cc1.w;
          float contrib = y * wg[j];
          contrib += __shfl_xor(contrib, 1);
          contrib += __shfl_xor(contrib, 2);
          contrib += __shfl_xor(contrib, 4);
          contrib += __shfl_xor(contrib, 8);
          contrib += __shfl_xor(contrib, 16);
          contrib += __shfl_xor(contrib, 32);
          if ((tid & 63) == 0) atomicAdd(&logit[rowbase + t], contrib);
        }
      }
    }
  }
}

// ---------------------------------------------------------------------------
// K4: threshold (sigmoid(lg)>0.5 <=> lg>0, exact) + 3x3 max pool. ego -> 1.
// ---------------------------------------------------------------------------
__global__ __launch_bounds__(128) void k4_pool(
    const float* __restrict__ logit, const int* __restrict__ slot,
    float* __restrict__ out)
{
  const int w = threadIdx.x;
  if (w >= W_IMG) return;
  const int hh = blockIdx.x;
  const int f = blockIdx.y;
  const int s = slot[f];
  float m = 0.0f;
  if (s < 0) {
    m = 1.0f;
  } else {
    for (int dh = -1; dh <= 1; ++dh) {
      const int h2 = hh + dh;
      if (h2 < 0 || h2 >= H_IMG) continue;
      for (int dw = -1; dw <= 1; ++dw) {
        const int w2 = w + dw;
        if (w2 < 0 || w2 >= W_IMG) continue;
        if (logit[(size_t)s * T_TOK + h2 * W_IMG + w2] > 0.0f) m = 1.0f;
      }
    }
  }
  out[(size_t)f * T_TOK + hh * W_IMG + w] = m;
}

// ---------------------------------------------------------------------------
extern "C" void kernel_launch(void* const* d_in, const int* in_sizes, int n_in,
                              void* d_out, int out_size, void* d_ws, size_t ws_size,
                              hipStream_t stream) {
  const float* feats      = (const float*)d_in[0];
  const float* in_proj    = (const float*)d_in[1];
  const float* conv_w     = (const float*)d_in[2];
  const float* conv_b     = (const float*)d_in[3];
  const float* x_proj_w   = (const float*)d_in[4];
  const float* dt_proj_w  = (const float*)d_in[5];
  const float* dt_proj_b  = (const float*)d_in[6];
  const float* A_log_f    = (const float*)d_in[7];
  const float* A_log_b    = (const float*)d_in[8];
  const float* D_f        = (const float*)d_in[9];
  const float* D_b        = (const float*)d_in[10];
  const float* out_proj_w = (const float*)d_in[11];
  const float* rms_w      = (const float*)d_in[12];
  const float* mlp_w      = (const float*)d_in[13];
  const float* mlp_b      = (const float*)d_in[14];
  const int*   rec        = (const int*)d_in[15];   // int32! (jax downcasts int64)

  const int N = in_sizes[0] / (C_CH * T_TOK);
  const int n_groups = in_sizes[15];
  int S = N - n_groups;
  if (S < 1) S = 1;

  // workspace carve-up
  char* p = (char*)d_ws;
  float* vvec  = (float*)p; p += 1024;
  int*   slot  = (int*)p;   p += ((N * 4 + 255) / 256) * 256;
  float* Bf    = (float*)p; p += C_CH * 256 * 4;
  float* logit = (float*)p; p += (size_t)S * T_TOK * 4;
  float* xipre = (float*)p; p += (size_t)S * T_TOK * C_CH * 4;
  float* wA    = (float*)p; p += (size_t)S * T_TOK * C_CH * 4;
  (void)ws_size; (void)n_in; (void)out_size;

  k0_setup<<<1, 256, 0, stream>>>(rec, n_groups, N, out_proj_w, mlp_w,
                                  in_proj, rms_w, vvec, slot, Bf);
  k1_gemm<<<dim3(T_TOK / MT, 2, N), 256, 0, stream>>>(
      feats, Bf, mlp_w, mlp_b, vvec, slot, xipre, wA, logit);
  k3_fused<<<dim3(T_TOK / CHUNK, N), 256, 0, stream>>>(
      xipre, wA, conv_w, conv_b, x_proj_w, dt_proj_w, dt_proj_b,
      A_log_f, A_log_b, D_f, D_b, slot, logit);
  k4_pool<<<dim3(H_IMG, N), 128, 0, stream>>>(logit, slot, (float*)d_out);
}